// Round 7
// baseline (172.099 us; speedup 1.0000x reference)
//
#include <hip/hip_runtime.h>
#include <hip/hip_fp16.h>

// VQC statevector simulator, v7: two samples per block, phase-interleaved.
// v6 counters: VALUBusy 68%, occupancy 21% (1 block/CU) -> remaining 32% is
// DS sweeps + barrier drain with nothing to overlap. v7 fills every barrier
// interval with the OTHER sample's butterfly VALU:
//   phase := { R(other sample's sweep); W(this sample's sweep); RX(other) ; bar }
// Sample A owns LDS buf0, B owns buf1 (64 KB each). Any R(bufX) and the next
// W(bufX) are in adjacent bar-intervals -> race-free via the single barrier.
// Weight sincos (56) computed once per block into an LDS table (threads 0-55)
// instead of per-thread (-56 sincos/thread).
//
// Layouts / addressing identical to v5/v6 (validated, absmax 3.9e-3):
//   L0: n=(t<<5)|o; L2: n=((t>>5)<<10)|(o<<5)|(t&31); L1: n=(o<<9)|t
//   CNOT chain == prefix-XOR perm, fused into encoding for layer 0.
//   swizzle swz(n)=n^((n>>6)&31) folded into thread constants.

typedef float v2f __attribute__((ext_vector_type(2)));

constexpr int NQ  = 14;
constexpr int DIM = 1 << NQ;     // 16384
constexpr int NT  = 512;         // 8 waves
constexpr int APT = DIM / NT;    // 32
constexpr int NL  = 4;

// ---- sweep address patterns (o = loop var), validated in v5/v6 ----
#define AD_PERMW (C_L1 ^ ((o << 9) | ((o & 3) << 3)))
#define AD_PERMR (C_PR ^ (o ^ (o << 1)))
#define AD_S1W   (C_L0 ^ o)
#define AD_S1R   (C_L2 ^ ((o << 5) | (o >> 1)))
#define AD_S2W   (C_L2 ^ ((o << 5) | (o >> 1)))
#define AD_S2R   (C_L1 ^ ((o << 9) | ((o & 3) << 3)))

#define WSWEEP(ARR, BUFI, WADDR)                                        \
    {                                                                   \
        __half2* buf_ = lds + (BUFI) * DIM;                             \
        _Pragma("unroll")                                               \
        for (int o = 0; o < APT; ++o)                                   \
            buf_[WADDR] = __floats2half2_rn(ARR[o].x, ARR[o].y);        \
    }

#define RSWEEP(ARR, BUFI, RADDR)                                        \
    {                                                                   \
        __half2* buf_ = lds + (BUFI) * DIM;                             \
        _Pragma("unroll")                                               \
        for (int o = 0; o < APT; ++o) {                                 \
            float2 f_ = __half22float2(buf_[RADDR]);                    \
            ARR[o].x = f_.x; ARR[o].y = f_.y;                           \
        }                                                               \
    }

// Packed butterfly on register bit QBIT with (s,c) pair SC (float2).
#define RXQ(ARR, QBIT, SC)                                              \
    {                                                                   \
        v2f sp; sp.x = (SC).x; sp.y = -(SC).x;                          \
        const float c_ = (SC).y;                                        \
        _Pragma("unroll")                                               \
        for (int o = 0; o < APT; ++o) {                                 \
            if (o & (1 << (QBIT))) continue;                            \
            const int o1 = o | (1 << (QBIT));                           \
            v2f w0 = ARR[o1].yx, w1 = ARR[o].yx;                        \
            ARR[o]  = __builtin_elementwise_fma(sp, w0, c_ * ARR[o]);   \
            ARR[o1] = __builtin_elementwise_fma(sp, w1, c_ * ARR[o1]);  \
        }                                                               \
    }

#define RX0_4(ARR, L)   { _Pragma("unroll") for (int q = 0; q < 5; ++q) { float2 sc_ = wtab[(L) * NQ + q];     RXQ(ARR, q,     sc_); } }
#define RX5_9(ARR, L)   { _Pragma("unroll") for (int q = 0; q < 5; ++q) { float2 sc_ = wtab[(L) * NQ + 5 + q]; RXQ(ARR, q,     sc_); } }
#define RX10_13(ARR, L) { _Pragma("unroll") for (int q = 10; q < NQ; ++q){ float2 sc_ = wtab[(L) * NQ + q];    RXQ(ARR, q - 9, sc_); } }

// Product-state encoding fused with layer-0 CNOT perm (into layout L0).
#define ENCODE(ARR, ROWPTR)                                             \
    {                                                                   \
        float cs_[NQ], sn_[NQ];                                         \
        _Pragma("unroll")                                               \
        for (int q = 0; q < NQ; ++q)                                    \
            __sincosf(0.5f * (ROWPTR)[q], &sn_[q], &cs_[q]);            \
        const int jbase_ = t << 5;                                      \
        const int srchi_ = (jbase_ ^ (jbase_ << 1)) & (DIM - 1);        \
        float base_ = 1.0f;                                             \
        _Pragma("unroll")                                               \
        for (int q = 6; q < NQ; ++q)                                    \
            base_ *= ((srchi_ >> q) & 1) ? sn_[q] : cs_[q];             \
        _Pragma("unroll")                                               \
        for (int o = 0; o < APT; ++o) {                                 \
            int j_   = jbase_ | o;                                      \
            int src_ = (j_ ^ (j_ << 1)) & (DIM - 1);                    \
            float v_ = base_;                                           \
            _Pragma("unroll")                                           \
            for (int q = 0; q < 6; ++q)                                 \
                v_ *= ((src_ >> q) & 1) ? sn_[q] : cs_[q];              \
            ARR[o].x = v_; ARR[o].y = 0.0f;                             \
        }                                                               \
    }

// Z-expectation partials (state in L1) -> RED[0..95] (12 floats x 8 waves).
#define EXPECT(ARR, RED)                                                \
    {                                                                   \
        float ptot = 0.0f, Sq[5] = {0, 0, 0, 0, 0};                     \
        _Pragma("unroll")                                               \
        for (int o = 0; o < APT; ++o) {                                 \
            float p = ARR[o].x * ARR[o].x + ARR[o].y * ARR[o].y;        \
            ptot += p;                                                  \
            _Pragma("unroll")                                           \
            for (int m = 0; m < 5; ++m)                                 \
                Sq[m] += ((o >> m) & 1) ? -p : p;                       \
        }                                                               \
        float accL[6];                                                  \
        _Pragma("unroll")                                               \
        for (int k = 0; k < 6; ++k) accL[k] = ptot;                     \
        _Pragma("unroll")                                               \
        for (int k = 0; k < 6; ++k) {                                   \
            const int m_ = 1 << k;                                      \
            _Pragma("unroll")                                           \
            for (int j = 0; j < 6; ++j) {                               \
                float pr = __shfl_xor(accL[j], m_, 64);                 \
                if (j == k)                                             \
                    accL[j] = ((lane >> k) & 1) ? (pr - accL[j])        \
                                                : (accL[j] - pr);       \
                else                                                    \
                    accL[j] += pr;                                      \
            }                                                           \
            ptot += __shfl_xor(ptot, m_, 64);                           \
            _Pragma("unroll")                                           \
            for (int j = 0; j < 5; ++j) Sq[j] += __shfl_xor(Sq[j], m_, 64); \
        }                                                               \
        if (lane == 0) {                                                \
            (RED)[wv * 12 + 0] = ptot;                                  \
            _Pragma("unroll")                                           \
            for (int k = 0; k < 6; ++k) (RED)[wv * 12 + 1 + k] = accL[k]; \
            _Pragma("unroll")                                           \
            for (int m = 0; m < 5; ++m) (RED)[wv * 12 + 7 + m] = Sq[m]; \
        }                                                               \
    }

__global__ __launch_bounds__(NT, 1)
void vqc_kernel(const float* __restrict__ inputs,
                const float* __restrict__ weights,
                float* __restrict__ out)
{
    extern __shared__ __half2 lds[];   // 2*DIM half2 (128 KB) + 1.5 KB tail
    const int t    = threadIdx.x;
    const int b    = blockIdx.x;
    const int lane = t & 63;
    const int wv   = t >> 6;
    const int sA   = 2 * b, sB = 2 * b + 1;

    float2* wtab = reinterpret_cast<float2*>(lds + 2 * DIM);            // 56 float2
    float*  red  = reinterpret_cast<float*>((char*)(lds + 2 * DIM) + 512); // 192 floats

    // Thread constants with swizzle pre-folded (half2-index space), from v5.
    const int C_L0 = (t << 5) | ((t >> 1) & 31);
    const int Tp   = ((t << 5) ^ (t << 6)) & (DIM - 1);
    const int C_PR = Tp ^ ((Tp >> 6) & 31);
    const int C_L2 = (((t >> 5) << 10) | (t & 31)) ^ (((t >> 5) & 1) << 4);
    const int C_L1 = t ^ ((t >> 6) & 7);

    // Weight sincos table: one sincos per (layer,qubit), threads 0..55.
    if (t < NL * NQ) {
        float s_, c_;
        __sincosf(0.5f * weights[t], &s_, &c_);
        wtab[t].x = s_; wtab[t].y = c_;
    }

    v2f aA[APT], aB[APT];
    ENCODE(aA, inputs + sA * NQ);
    ENCODE(aB, inputs + sB * NQ);
    __syncthreads();                       // wtab visible to all

    RX0_4(aA, 0);
    // phase 0
    WSWEEP(aA, 0, AD_S1W);  RX0_4(aB, 0);  __syncthreads();
    // phase 1
    RSWEEP(aA, 0, AD_S1R);  WSWEEP(aB, 1, AD_S1W);  RX5_9(aA, 0);  __syncthreads();
    // phase 2
    RSWEEP(aB, 1, AD_S1R);  WSWEEP(aA, 0, AD_S2W);  RX5_9(aB, 0);  __syncthreads();
    // phase 3
    RSWEEP(aA, 0, AD_S2R);  WSWEEP(aB, 1, AD_S2W);  RX10_13(aA, 0); __syncthreads();

#pragma unroll 1
    for (int l = 1; l < NL; ++l) {
        RSWEEP(aB, 1, AD_S2R);  WSWEEP(aA, 0, AD_PERMW); RX10_13(aB, l - 1); __syncthreads();
        RSWEEP(aA, 0, AD_PERMR); WSWEEP(aB, 1, AD_PERMW); RX0_4(aA, l);      __syncthreads();
        RSWEEP(aB, 1, AD_PERMR); WSWEEP(aA, 0, AD_S1W);   RX0_4(aB, l);      __syncthreads();
        RSWEEP(aA, 0, AD_S1R);   WSWEEP(aB, 1, AD_S1W);   RX5_9(aA, l);      __syncthreads();
        RSWEEP(aB, 1, AD_S1R);   WSWEEP(aA, 0, AD_S2W);   RX5_9(aB, l);      __syncthreads();
        RSWEEP(aA, 0, AD_S2R);   WSWEEP(aB, 1, AD_S2W);   RX10_13(aA, l);    __syncthreads();
    }
    // epilogue: B's last read + final butterflies
    RSWEEP(aB, 1, AD_S2R);  RX10_13(aB, NL - 1);

    EXPECT(aA, red);
    EXPECT(aB, red + 96);
    __syncthreads();

    // Final cross-wave combine. State was in L1: canonical bits 0-5 = lane
    // (qubits 0-5), 6-8 = wave (qubits 6-8), 9-13 = o bits (qubits 9-13).
    if (t < NQ) {
        float accA = 0.0f, accB = 0.0f;
        if (t < 6) {
            for (int w = 0; w < 8; ++w) { accA += red[w * 12 + 1 + t]; accB += red[96 + w * 12 + 1 + t]; }
        } else if (t < 9) {
            const int bit = t - 6;
            for (int w = 0; w < 8; ++w) {
                float vA = red[w * 12], vB = red[96 + w * 12];
                accA += ((w >> bit) & 1) ? -vA : vA;
                accB += ((w >> bit) & 1) ? -vB : vB;
            }
        } else {
            for (int w = 0; w < 8; ++w) { accA += red[w * 12 + 7 + (t - 9)]; accB += red[96 + w * 12 + 7 + (t - 9)]; }
        }
        out[sA * NQ + t] = accA;
        out[sB * NQ + t] = accB;
    }
}

extern "C" void kernel_launch(void* const* d_in, const int* in_sizes, int n_in,
                              void* d_out, int out_size, void* d_ws, size_t ws_size,
                              hipStream_t stream)
{
    const float* inputs  = (const float*)d_in[0];
    const float* weights = (const float*)d_in[1];
    float* out = (float*)d_out;

    const int Bn = in_sizes[0] / NQ;   // 1024
    const size_t shmem = 2 * DIM * sizeof(__half2) + 1536;
    vqc_kernel<<<dim3(Bn / 2), dim3(NT), shmem, stream>>>(inputs, weights, out);
}

// Round 8
// 109.414 us; speedup vs baseline: 1.5729x; 1.5729x over previous
//
#include <hip/hip_runtime.h>
#include <hip/hip_fp16.h>

// VQC statevector simulator, v8 = v6 + b64 LDS sweeps + weight-sincos table.
// v7 regressed (2-sample interleave needs ~190 VGPR; hipcc caps 8-wave blocks
// at 128 even with launch_bounds(512,1) -> spill). v8 reverts to v6 structure
// and attacks the DS pipe: 704 -> 464 DS ops/thread via paired (8B) accesses.
//
// Per-sweep linear address maps (each sweep owns its LDS image; write/read
// only must agree within the sweep). b64 pairing requires map(delta)=1 for the
// pair's canonical-index offset delta:
//  - S2 (L2->L1): shared canonical bit 9 in both windows -> BOTH sides b64.
//  - S1 (L0->L2): windows disjoint -> read-side b64 (delta = 1<<5), write b32.
//  - PERM (L1->L0, CNOT perm folded in read): pi spreads any bit flip over two
//    bits -> read must stay b32; write-side b64 (delta = 1<<9).
// Bank spread checked per instruction: b32 sides <=2 lanes/bank, b64 sides
// 4 words/bank (= 512B/128B-per-clock streaming optimum).
//
// Layouts (canonical bit k = qubit k):
//   L0: n = (t<<5)|o            (o = qubits 0-4)
//   L2: n = ((t>>5)<<10)|(o<<5)|(t&31)   (o = qubits 5-9)
//   L1: n = (o<<9)|t            (o = qubits 9-13)
// CNOT chain == prefix-XOR perm, src = (j ^ (j<<1)) & 0x3FFF; layer-0 perm
// fused into the product-state encoding (validated v5-v7, absmax 3.9e-3).
// LDS: 2 x 64 KB double buffer (one barrier per sweep, v6 induction) + tail
// for weight table (56 float2) and reduction scratch.

typedef float v2f __attribute__((ext_vector_type(2)));

constexpr int NQ  = 14;
constexpr int DIM = 1 << NQ;     // 16384
constexpr int NT  = 512;         // 8 waves
constexpr int APT = DIM / NT;    // 32
constexpr int NL  = 4;

static __device__ __forceinline__ unsigned pk(v2f v) {
    __half2 h = __floats2half2_rn(v.x, v.y);
    return *reinterpret_cast<unsigned*>(&h);
}
static __device__ __forceinline__ v2f upk(unsigned u) {
    __half2 h = *reinterpret_cast<__half2*>(&u);
    float2 f = __half22float2(h);
    v2f r; r.x = f.x; r.y = f.y; return r;
}

// Packed RX butterfly on register bit QBIT with (s,c) in SC (float2: x=s,y=c).
#define RXQ(QBIT, SC)                                                   \
    {                                                                   \
        v2f sp; sp.x = (SC).x; sp.y = -(SC).x;                          \
        const float c_ = (SC).y;                                        \
        _Pragma("unroll")                                               \
        for (int o = 0; o < APT; ++o) {                                 \
            if (o & (1 << (QBIT))) continue;                            \
            const int o1 = o | (1 << (QBIT));                           \
            v2f w0 = a[o1].yx, w1 = a[o].yx;                            \
            a[o]  = __builtin_elementwise_fma(sp, w0, c_ * a[o]);       \
            a[o1] = __builtin_elementwise_fma(sp, w1, c_ * a[o1]);      \
        }                                                               \
    }

#define RX0_4(L)   { _Pragma("unroll") for (int q = 0; q < 5; ++q)  { float2 sc_ = wtab[(L) * NQ + q];     RXQ(q, sc_); } }
#define RX5_9(L)   { _Pragma("unroll") for (int q = 0; q < 5; ++q)  { float2 sc_ = wtab[(L) * NQ + 5 + q]; RXQ(q, sc_); } }
#define RX10_13(L) { _Pragma("unroll") for (int q = 10; q < NQ; ++q){ float2 sc_ = wtab[(L) * NQ + q];     RXQ(q - 9, sc_); } }

// S1: L0 -> L2. Write b32 at C1w ^ (((o&15)<<1)|(o<<5)); read b64 at C1r ^ o.
#define SWEEP_S1                                                        \
    {                                                                   \
        __half2* buf = lds + pb * DIM;                                  \
        uint2* buf64 = reinterpret_cast<uint2*>(buf);                   \
        _Pragma("unroll")                                               \
        for (int o = 0; o < APT; ++o) {                                 \
            __half2 h = __floats2half2_rn(a[o].x, a[o].y);              \
            buf[C1w ^ (((o & 15) << 1) | (o << 5))] = h;                \
        }                                                               \
        __syncthreads();                                                \
        _Pragma("unroll")                                               \
        for (int o = 0; o < APT; o += 2) {                              \
            uint2 r_ = buf64[(C1r ^ o) >> 1];                           \
            a[o] = upk(r_.x); a[o + 1] = upk(r_.y);                     \
        }                                                               \
        pb ^= 1;                                                        \
    }

// S2: L2 -> L1. Both sides b64 (shared canonical bit 9).
// Write pairs (o, o+16) at C2w ^ (o<<7); read pairs (o, o+1) at
// C2r ^ ((((o>>1)&1)<<6) | (((o>>2)&7)<<11)).
#define SWEEP_S2                                                        \
    {                                                                   \
        uint2* buf64 = reinterpret_cast<uint2*>(lds + pb * DIM);        \
        _Pragma("unroll")                                               \
        for (int o = 0; o < 16; ++o)                                    \
            buf64[(C2w ^ (o << 7)) >> 1] =                              \
                make_uint2(pk(a[o]), pk(a[o + 16]));                    \
        __syncthreads();                                                \
        _Pragma("unroll")                                               \
        for (int o = 0; o < APT; o += 2) {                              \
            uint2 r_ = buf64[(C2r ^ ((((o >> 1) & 1) << 6)              \
                                   | (((o >> 2) & 7) << 11))) >> 1];    \
            a[o] = upk(r_.x); a[o + 1] = upk(r_.y);                     \
        }                                                               \
        pb ^= 1;                                                        \
    }

// PERM: L1 -> L0 with CNOT-chain perm folded into the read.
// Write pairs (o, o+1) b64 at Cpw ^ (((o>>1)&15)<<10); read b32 at
// ApT ^ Ap(o ^ (o<<1)).
#define SWEEP_PERM                                                      \
    {                                                                   \
        __half2* buf = lds + pb * DIM;                                  \
        uint2* buf64 = reinterpret_cast<uint2*>(buf);                   \
        _Pragma("unroll")                                               \
        for (int o = 0; o < APT; o += 2)                                \
            buf64[(Cpw ^ (((o >> 1) & 15) << 10)) >> 1] =               \
                make_uint2(pk(a[o]), pk(a[o + 1]));                     \
        __syncthreads();                                                \
        _Pragma("unroll")                                               \
        for (int o = 0; o < APT; ++o) {                                 \
            const int O_   = (o ^ (o << 1)) & 0x3F;                     \
            const int ApO_ = ((((O_ & 15) ^ ((O_ >> 5) & 15))) << 1)    \
                           | ((O_ & 31) << 5);                          \
            float2 f_ = __half22float2(buf[ApT ^ ApO_]);                \
            a[o].x = f_.x; a[o].y = f_.y;                               \
        }                                                               \
        pb ^= 1;                                                        \
    }

__global__ __launch_bounds__(NT, 1)
void vqc_kernel(const float* __restrict__ inputs,
                const float* __restrict__ weights,
                float* __restrict__ out)
{
    extern __shared__ __half2 lds[];   // 2*DIM half2 (128 KB) + 1.5 KB tail
    const int t    = threadIdx.x;
    const int b    = blockIdx.x;
    const int lane = t & 63;
    const int wv   = t >> 6;

    float2* wtab = reinterpret_cast<float2*>(lds + 2 * DIM);               // 56 float2
    float*  red  = reinterpret_cast<float*>((char*)(lds + 2 * DIM) + 512); // 96 floats

    // ---- per-sweep thread-constant address bases (derived maps, see header) ----
    // S1 (A1: a0=c5; a(k+1)=ck^c(k+6) k=0..3; a5-9=c0-4; a10-13=c10-13)
    const int C1w = (t & 31) | (((t >> 5) & 15) << 10);
    const int C1r = ((t & 15) << 1) | ((t & 31) << 5) | (((t >> 5) & 15) << 10);
    // S2 (A2: pure bit permutation, a0=c9)
    const int C2w = ((t & 15) << 1) | (((t >> 4) & 1) << 5) | (((t >> 5) & 1) << 6)
                  | (((t >> 6) & 7) << 11);
    const int C2r = ((t & 15) << 1) | (((t >> 4) & 1) << 5) | (((t >> 5) & 15) << 7);
    // PERM (Ap: a0=c9; a(k+1)=ck^c(k+5) k=0..3; a5-9=c0-4; a10-13=c10-13)
    const int Cpw = (((t & 15) ^ ((t >> 5) & 15)) << 1) | ((t & 31) << 5);
    const int Tm  = ((t << 5) ^ (t << 6)) & (DIM - 1);
    const int ApT = ((Tm >> 9) & 1)
                  | ((((Tm & 15) ^ ((Tm >> 5) & 15))) << 1)
                  | ((Tm & 31) << 5)
                  | (((Tm >> 10) & 15) << 10);

    // Weight sincos table: one per (layer,qubit), threads 0..55.
    if (t < NL * NQ) {
        float s_, c_;
        __sincosf(0.5f * weights[t], &s_, &c_);
        wtab[t].x = s_; wtab[t].y = c_;
    }

    v2f a[APT];

    // ---- Encoding fused with layer-0 CNOT perm: product state built in L0 ----
    {
        float cs[NQ], sn[NQ];
#pragma unroll
        for (int q = 0; q < NQ; ++q)
            __sincosf(0.5f * inputs[b * NQ + q], &sn[q], &cs[q]);

        const int jbase = t << 5;
        const int srchi = (jbase ^ (jbase << 1)) & (DIM - 1);
        float base = 1.0f;
#pragma unroll
        for (int q = 6; q < NQ; ++q)
            base *= ((srchi >> q) & 1) ? sn[q] : cs[q];
#pragma unroll
        for (int o = 0; o < APT; ++o) {
            int j   = jbase | o;
            int src = (j ^ (j << 1)) & (DIM - 1);
            float v = base;
#pragma unroll
            for (int q = 0; q < 6; ++q)
                v *= ((src >> q) & 1) ? sn[q] : cs[q];
            a[o].x = v; a[o].y = 0.0f;
        }
    }

    __syncthreads();   // wtab visible

    int pb = 0;        // double-buffer parity; 11 sweeps total

    // Layer 0 (perm fused into encoding)
    RX0_4(0);
    SWEEP_S1;          // sweep 0
    RX5_9(0);
    SWEEP_S2;          // sweep 1
    RX10_13(0);

#pragma unroll 1
    for (int l = 1; l < NL; ++l) {
        SWEEP_PERM;    // L1 -> L0 (+pi)
        RX0_4(l);
        SWEEP_S1;
        RX5_9(l);
        SWEEP_S2;
        RX10_13(l);
    }

    // ---- Z expectations. State in L1: canonical bits 0-5 = lane (qubits 0-5),
    //      6-8 = wave (qubits 6-8), 9-13 = o bits (qubits 9-13). ----
    float ptot = 0.0f, Sq[5] = {0, 0, 0, 0, 0};
#pragma unroll
    for (int o = 0; o < APT; ++o) {
        float p = a[o].x * a[o].x + a[o].y * a[o].y;
        ptot += p;
#pragma unroll
        for (int m = 0; m < 5; ++m)
            Sq[m] += ((o >> m) & 1) ? -p : p;
    }

    // Wave-level butterfly: plain sums for ptot/Sq, signed (Walsh) for lane qubits 0..5.
    float accL[6];
#pragma unroll
    for (int k = 0; k < 6; ++k) accL[k] = ptot;
#pragma unroll
    for (int k = 0; k < 6; ++k) {
        const int m = 1 << k;
#pragma unroll
        for (int j = 0; j < 6; ++j) {
            float pr = __shfl_xor(accL[j], m, 64);
            if (j == k)
                accL[j] = ((lane >> k) & 1) ? (pr - accL[j]) : (accL[j] - pr);
            else
                accL[j] += pr;
        }
        ptot += __shfl_xor(ptot, m, 64);
#pragma unroll
        for (int j = 0; j < 5; ++j) Sq[j] += __shfl_xor(Sq[j], m, 64);
    }

    // Per-wave partials -> tail scratch (disjoint from state buffers).
    if (lane == 0) {
        red[wv * 12 + 0] = ptot;
#pragma unroll
        for (int k = 0; k < 6; ++k) red[wv * 12 + 1 + k] = accL[k];   // qubits 0..5
#pragma unroll
        for (int m = 0; m < 5; ++m) red[wv * 12 + 7 + m] = Sq[m];     // qubits 9..13
    }
    __syncthreads();

    if (t < NQ) {
        float acc = 0.0f;
        if (t < 6) {
            for (int w = 0; w < 8; ++w) acc += red[w * 12 + 1 + t];
        } else if (t < 9) {
            const int bit = t - 6;
            for (int w = 0; w < 8; ++w) {
                float v = red[w * 12];
                acc += ((w >> bit) & 1) ? -v : v;
            }
        } else {
            for (int w = 0; w < 8; ++w) acc += red[w * 12 + 7 + (t - 9)];
        }
        out[b * NQ + t] = acc;
    }
}

extern "C" void kernel_launch(void* const* d_in, const int* in_sizes, int n_in,
                              void* d_out, int out_size, void* d_ws, size_t ws_size,
                              hipStream_t stream)
{
    const float* inputs  = (const float*)d_in[0];
    const float* weights = (const float*)d_in[1];
    float* out = (float*)d_out;

    const int Bn = in_sizes[0] / NQ;   // 1024
    const size_t shmem = 2 * DIM * sizeof(__half2) + 1536;
    vqc_kernel<<<dim3(Bn), dim3(NT), shmem, stream>>>(inputs, weights, out);
}

// Round 9
// 108.790 us; speedup vs baseline: 1.5819x; 1.0057x over previous
//
#include <hip/hip_runtime.h>
#include <hip/hip_fp16.h>

// VQC statevector simulator, v9: fp16 packed state + 2-sample interleave.
// v8 counters: DS and VALU serialized (VALU 78us + DS ~37us ~= 125us dur).
// v9: amplitude = one __half2 in ONE VGPR -> two samples fit in registers
// (2x32 = 64 regs state, <=128 cap). Every phase runs one sample's sweep
// (DS) against the other sample's RX butterflies (VALU), one barrier/phase.
// Butterflies in native packed fp16 (v_pk_fma_f16); sweeps have zero cvts.
//
// Windows (canonical bit q = qubit q), NT=512 (t = 9 bits):
//  P0: n = o | ((t&3)<<5) | (((t>>2)&15)<<7) | ((t>>6)<<11)
//      reg o = q0-4; lane0,1 = q5,q6 (RX via v_mov_dpp quad_perm); rest passive
//  P1: n = (o<<7) | ((t&3)<<12) | ((t>>2)&15) | (((t>>6)&7)<<4)
//      reg o = q7-11; lane0,1 = q12,q13
// Per layer: RXlow(q0-6 in P0), S1: P0->P1, RXhigh(q7-13 in P1), S2: P1->P0
// with CNOT-chain perm (src = (j^(j<<1)) & 0x3FFF) folded into the read.
// Layer-0 perm fused into product-state encoding. 7 sweeps/sample.
//
// Per-sweep bijective XOR address maps (derived + bank-checked):
//  S1:  a0=c0; a1=c1^c5; a2=c2^c6; a3=c3^c7^c13; a4=c4^c8^c12; a5-9=c9..c13;
//       a10-13=c1..c4.  Write b64 (pair c0): 4 words/bank optimal; read b32 2-way.
//  S2:  a0=c7; a1=c0^c8; a2=c1^c9; a3=c2^c10; a4=c3^c6^c12; a5-7=c4,c5,c6;
//       a8=c11; a9=c13; a10-12=c8..c10; a13=c12.  Write b64 4/bank; perm-read
//       b32 2-way (read addr = CR2 ^ ((o^(o<<1))<<1)).
// Sample A owns buf0, B owns buf1; each buffer alternates W/R across adjacent
// barrier intervals -> race-free with 1 barrier per phase.

typedef unsigned int u32;

constexpr int NQ  = 14;
constexpr int DIM = 1 << NQ;     // 16384
constexpr int NT  = 512;         // 8 waves
constexpr int APT = DIM / NT;    // 32 amps (one __half2 each)
constexpr int NL  = 4;

#define H2U(v) __builtin_bit_cast(u32, v)
#define U2H(v) __builtin_bit_cast(__half2, v)
// quad_perm lane^1 = [1,0,3,2] = 0xB1 ; lane^2 = [2,3,0,1] = 0x4E
#define DPP1(v) U2H((u32)__builtin_amdgcn_mov_dpp((int)H2U(v), 0xB1, 0xF, 0xF, true))
#define DPP2(v) U2H((u32)__builtin_amdgcn_mov_dpp((int)H2U(v), 0x4E, 0xF, 0xF, true))

#define TB(k) ((t >> (k)) & 1)
#define TM(k) ((Tm >> (k)) & 1)

// a' = c*a + s*J(partner), J(x,y) = (y,-x); sp = (s,-s), cc = (c,c).
#define LOADSC(L, Q) { float2 sc_ = wtab[(L) * NQ + (Q)];               \
    sp_ = __floats2half2_rn(sc_.x, -sc_.x);                             \
    cc_ = __float2half2_rn(sc_.y); }

#define RXBIT(ARR, BIT) { _Pragma("unroll")                             \
    for (int o = 0; o < APT; ++o) {                                     \
        if (o & (1 << (BIT))) continue;                                 \
        const int o1_ = o | (1 << (BIT));                               \
        __half2 t0_ = ARR[o], t1_ = ARR[o1_];                           \
        ARR[o]   = __hfma2(sp_, __lowhigh2highlow(t1_), __hmul2(cc_, t0_)); \
        ARR[o1_] = __hfma2(sp_, __lowhigh2highlow(t0_), __hmul2(cc_, t1_)); } }

#define RXD(ARR, DPPM) { _Pragma("unroll")                              \
    for (int o = 0; o < APT; ++o) {                                     \
        __half2 p_ = DPPM(ARR[o]);                                      \
        ARR[o] = __hfma2(sp_, __lowhigh2highlow(p_), __hmul2(cc_, ARR[o])); } }

#define RXLOW(ARR, L)  { __half2 sp_, cc_;                              \
    LOADSC(L,0)  RXBIT(ARR,0) LOADSC(L,1)  RXBIT(ARR,1)                 \
    LOADSC(L,2)  RXBIT(ARR,2) LOADSC(L,3)  RXBIT(ARR,3)                 \
    LOADSC(L,4)  RXBIT(ARR,4) LOADSC(L,5)  RXD(ARR,DPP1)                \
    LOADSC(L,6)  RXD(ARR,DPP2) }
#define RXHIGH(ARR, L) { __half2 sp_, cc_;                              \
    LOADSC(L,7)  RXBIT(ARR,0) LOADSC(L,8)  RXBIT(ARR,1)                 \
    LOADSC(L,9)  RXBIT(ARR,2) LOADSC(L,10) RXBIT(ARR,3)                 \
    LOADSC(L,11) RXBIT(ARR,4) LOADSC(L,12) RXD(ARR,DPP1)                \
    LOADSC(L,13) RXD(ARR,DPP2) }

// Sweeps (addresses = threadConst ^ compileTimeConst(o))
#define WS1(ARR, BUF) { uint2* b2_ = reinterpret_cast<uint2*>(BUF);     \
    _Pragma("unroll") for (int o = 0; o < APT; o += 2)                  \
        b2_[(CW1 ^ (o | (((o >> 1) & 15) << 10))) >> 1] =               \
            make_uint2(H2U(ARR[o]), H2U(ARR[o + 1])); }
#define RS1(ARR, BUF) { _Pragma("unroll") for (int o = 0; o < APT; ++o) \
        ARR[o] = (BUF)[CR1 ^ (((o & 1) << 3) | (((o >> 1) & 15) << 4))]; }
#define WS2(ARR, BUF) { uint2* b2_ = reinterpret_cast<uint2*>(BUF);     \
    _Pragma("unroll") for (int o = 0; o < APT; o += 2)                  \
        b2_[(CW2 ^ ((o & 15) | (((o >> 4) & 1) << 8) | (((o >> 1) & 7) << 10))) >> 1] = \
            make_uint2(H2U(ARR[o]), H2U(ARR[o + 1])); }
#define RS2(ARR, BUF) { _Pragma("unroll") for (int o = 0; o < APT; ++o) { \
        const int op_ = (o ^ (o << 1)) & 63;                            \
        ARR[o] = (BUF)[CR2 ^ (op_ << 1)]; } }

// Product-state encoding with layer-0 CNOT perm fused, into P0.
// src bits 6..13 = Tm bits 1..8 (thread-only); src 0..4 = op bits; src5 = op5^t0.
#define ENCODE(ARR, ROW) {                                              \
    float cs_[NQ], sn_[NQ];                                             \
    _Pragma("unroll") for (int q = 0; q < NQ; ++q)                      \
        __sincosf(0.5f * (ROW)[q], &sn_[q], &cs_[q]);                   \
    float base_ = 1.0f;                                                 \
    _Pragma("unroll") for (int q = 6; q < NQ; ++q)                      \
        base_ *= ((Tm >> (q - 5)) & 1) ? sn_[q] : cs_[q];               \
    _Pragma("unroll") for (int o = 0; o < APT; ++o) {                   \
        const int op_ = o ^ (o << 1);                                   \
        float v_ = base_;                                               \
        _Pragma("unroll") for (int q = 0; q < 5; ++q)                   \
            v_ *= ((op_ >> q) & 1) ? sn_[q] : cs_[q];                   \
        v_ *= (((op_ >> 5) ^ t) & 1) ? sn_[5] : cs_[5];                 \
        ARR[o] = __floats2half2_rn(v_, 0.0f); } }

// Z-expectation partials from P1 layout -> RED[wave*12 + 0..11].
// lane bit k <-> qubit: 0->q12 1->q13 2->q0 3->q1 4->q2 5->q3; o bit m -> q7+m.
#define EXPECT(ARR, RED) {                                              \
    float ptot = 0.f, Sq[5] = {0, 0, 0, 0, 0};                          \
    _Pragma("unroll") for (int o = 0; o < APT; ++o) {                   \
        float2 f_ = __half22float2(ARR[o]);                             \
        float p_ = f_.x * f_.x + f_.y * f_.y;                           \
        ptot += p_;                                                     \
        _Pragma("unroll") for (int m = 0; m < 5; ++m)                   \
            Sq[m] += ((o >> m) & 1) ? -p_ : p_; }                       \
    float accL[6];                                                      \
    _Pragma("unroll") for (int k = 0; k < 6; ++k) accL[k] = ptot;       \
    _Pragma("unroll") for (int k = 0; k < 6; ++k) {                     \
        const int m_ = 1 << k;                                          \
        _Pragma("unroll") for (int j = 0; j < 6; ++j) {                 \
            float pr_ = __shfl_xor(accL[j], m_, 64);                    \
            if (j == k) accL[j] = ((lane >> k) & 1) ? (pr_ - accL[j])   \
                                                    : (accL[j] - pr_);  \
            else accL[j] += pr_; }                                      \
        ptot += __shfl_xor(ptot, m_, 64);                               \
        _Pragma("unroll") for (int j2 = 0; j2 < 5; ++j2)                \
            Sq[j2] += __shfl_xor(Sq[j2], m_, 64); }                     \
    if (lane == 0) {                                                    \
        (RED)[wv * 12 + 0] = ptot;                                      \
        _Pragma("unroll") for (int k = 0; k < 6; ++k) (RED)[wv * 12 + 1 + k] = accL[k]; \
        _Pragma("unroll") for (int m2 = 0; m2 < 5; ++m2) (RED)[wv * 12 + 7 + m2] = Sq[m2]; } }

__global__ __launch_bounds__(NT, 2)
void vqc_kernel(const float* __restrict__ inputs,
                const float* __restrict__ weights,
                float* __restrict__ out)
{
    extern __shared__ __half2 lds[];            // buf0 | buf1 | wtab | redA | redB
    const int t    = threadIdx.x;
    const int b    = blockIdx.x;
    const int lane = t & 63;
    const int wv   = t >> 6;
    const int sA   = 2 * b, sB = 2 * b + 1;
    const int Tm   = (t ^ (t << 1)) & 0x3FF;    // thread prefix-xor bits

    __half2* buf0 = lds;
    __half2* buf1 = lds + DIM;
    float2*  wtab = reinterpret_cast<float2*>(lds + 2 * DIM);   // 56 entries
    float*   redA = reinterpret_cast<float*>(wtab + 56);        // 96 floats
    float*   redB = redA + 96;                                  // 96 floats

    // Per-sweep thread-constant address bases (see map derivation in header).
    const int CW1 = ((t & 3) << 1) | ((TB(2) ^ TB(8)) << 3) | ((TB(3) ^ TB(7)) << 4)
                  | (((t >> 4) & 7) << 5) | (((t >> 7) & 3) << 8);
    const int CR1 = TB(2) | ((TB(3) ^ TB(7)) << 1) | ((TB(4) ^ TB(8)) << 2)
                  | ((TB(5) ^ TB(1)) << 3) | ((TB(6) ^ TB(0)) << 4)
                  | (TB(0) << 8) | (TB(1) << 9) | (TB(3) << 10) | (TB(4) << 11)
                  | (TB(5) << 12) | (TB(6) << 13);
    const int CW2 = (TB(2) << 1) | (TB(3) << 2) | (TB(4) << 3)
                  | ((TB(5) ^ TB(8) ^ TB(0)) << 4) | (TB(6) << 5) | (TB(7) << 6)
                  | (TB(8) << 7) | (TB(1) << 9) | (TB(0) << 13);
    const int CR2 = TM(2) | (TM(3) << 1) | (TM(4) << 2) | (TM(5) << 3)
                  | ((TM(1) ^ TM(7)) << 4) | (TM(0) << 6) | (TM(1) << 7)
                  | (TM(6) << 8) | (TM(8) << 9) | (TM(3) << 10) | (TM(4) << 11)
                  | (TM(5) << 12) | (TM(7) << 13);

    // Weight sincos table (one per layer x qubit).
    if (t < NL * NQ) {
        float s_, c_;
        __sincosf(0.5f * weights[t], &s_, &c_);
        wtab[t].x = s_; wtab[t].y = c_;
    }

    __half2 aA[APT], aB[APT];
    ENCODE(aA, inputs + sA * NQ);
    ENCODE(aB, inputs + sB * NQ);
    __syncthreads();                                   // wtab visible

    RXLOW(aA, 0);
    // ph1
    WS1(aA, buf0);                  RXLOW(aB, 0);   __syncthreads();
    // ph2
    RS1(aA, buf0); WS1(aB, buf1);   RXHIGH(aA, 0);  __syncthreads();
    // ph3
    RS1(aB, buf1); WS2(aA, buf0);   RXHIGH(aB, 0);  __syncthreads();

#pragma unroll 1
    for (int l = 1; l < NL; ++l) {
        RS2(aA, buf0); WS2(aB, buf1);  RXLOW(aA, l);   __syncthreads();  // ph4
        RS2(aB, buf1); WS1(aA, buf0);  RXLOW(aB, l);   __syncthreads();  // ph5
        RS1(aA, buf0); WS1(aB, buf1);  RXHIGH(aA, l);  __syncthreads();  // ph6
        RS1(aB, buf1); WS2(aA, buf0);  RXHIGH(aB, l);  __syncthreads();  // ph7
        // (l==3: the WS2(aA) write is unused but harmless -- keeps phases uniform)
    }

    EXPECT(aA, redA);
    EXPECT(aB, redB);
    __syncthreads();

    // Cross-wave combine. Wave bits w0-2 = qubits 4-6 (P1 layout).
    if (t < NQ) {
        float accA = 0.f, accB = 0.f;
#pragma unroll 1
        for (int w = 0; w < 8; ++w) {
            float vA, vB;
            if (t < 4)       { vA = redA[w * 12 + 3 + t];        vB = redB[w * 12 + 3 + t]; }
            else if (t < 7)  { vA = redA[w * 12];                vB = redB[w * 12];
                               if ((w >> (t - 4)) & 1) { vA = -vA; vB = -vB; } }
            else if (t < 12) { vA = redA[w * 12 + 7 + (t - 7)];  vB = redB[w * 12 + 7 + (t - 7)]; }
            else             { vA = redA[w * 12 + 1 + (t - 12)]; vB = redB[w * 12 + 1 + (t - 12)]; }
            accA += vA; accB += vB;
        }
        out[sA * NQ + t] = accA;
        out[sB * NQ + t] = accB;
    }
}

extern "C" void kernel_launch(void* const* d_in, const int* in_sizes, int n_in,
                              void* d_out, int out_size, void* d_ws, size_t ws_size,
                              hipStream_t stream)
{
    const float* inputs  = (const float*)d_in[0];
    const float* weights = (const float*)d_in[1];
    float* out = (float*)d_out;

    const int Bn = in_sizes[0] / NQ;   // 1024
    const size_t shmem = 2 * DIM * sizeof(__half2) + 56 * sizeof(float2) + 192 * sizeof(float);
    vqc_kernel<<<dim3(Bn / 2), dim3(NT), shmem, stream>>>(inputs, weights, out);
}

// Round 10
// 99.341 us; speedup vs baseline: 1.7324x; 1.0951x over previous
//
#include <hip/hip_runtime.h>
#include <hip/hip_fp16.h>

// VQC statevector simulator, v10: pipelined 2-sample fp16 + op_sel RX +
// read2-merged conflict-free sweeps + LDS sincos tables.
//
// One block = 2 samples. 512 threads x 32 amps (__half2 re,im) per sample.
// Windows (canonical bit q = qubit q), t = 9 thread bits t0..t8:
//  P0: q0-4 = reg o; q5,q6 = t0,t1 (DPP quad_perm); q7-13 = t2..t8.
//  P1: q7-11 = reg o; q12,q13 = t0,t1 (DPP); q0-6 = t2..t8.
// Per layer per sample: RXLOW(q0-6 in P0) -> S1(P0->P1) -> RXHIGH(q7-13 in P1)
// -> S2(P1->P0, CNOT-chain perm src=(n^(n<<1))&mask folded into read).
// Layer-0 perm fused into the product-state encoding (validated v5-v9).
//
// Sweep address maps (14-bit GF(2), derived + spot-verified):
//  S1 rows: e0={c0} e1={c5,c12} e2={c6,c13} e3={c8,c1} e4={c9,c2} e5={c7}
//           e6={c3} e7={c4} e8={c10} e9={c11} e10={c5} e11={c6} e12={c8} e13={c9}
//  S2 rows: e0={c7} e1={c12,c8} e2={c13,c9} e3={c2,c10} e4={c3,c11} e5={c0}
//           e6={c1} e7={c4} e8={c5} e9={c6} e10={c8} e11={c9} e12={c10} e13={c11}
// Both sweeps: write = ds_write_b64 pairs (addr bit0 = write-window bit0);
// read = two b32 loads off one base with compile-time dword offsets (0/32 for
// S1; {0,96}/{64,32} for S2) -> LLVM merges to ds_read2_b32. Every inst lands
// exactly 4 dwords/bank (checked): zero bank conflicts.
//
// Phase schedule (true pipeline): {RS(X); RX(Y from prev phase); WS(Y); bar}.
// Buffer A=buf0, B=buf1 alternate R/W in adjacent barrier intervals: race-free.

typedef unsigned int u32;

constexpr int NQ  = 14;
constexpr int DIM = 1 << NQ;     // 16384
constexpr int NT  = 512;         // 8 waves
constexpr int APT = DIM / NT;    // 32
constexpr int NL  = 4;

#define H2U(v) __builtin_bit_cast(u32, v)
#define U2H(v) __builtin_bit_cast(__half2, v)
// quad_perm lane^1 = 0xB1, lane^2 = 0x4E
#define DPP1(v) U2H((u32)__builtin_amdgcn_mov_dpp((int)H2U(v), 0xB1, 0xF, 0xF, true))
#define DPP2(v) U2H((u32)__builtin_amdgcn_mov_dpp((int)H2U(v), 0x4E, 0xF, 0xF, true))

// d.lo = s.lo*p.hi + t.lo ; d.hi = s.hi*p.lo + t.hi  (swap fused via op_sel)
static __device__ __forceinline__ __half2 fma_sw(__half2 s, __half2 p, __half2 t) {
    u32 d, su = H2U(s), pu = H2U(p), tu = H2U(t);
    asm("v_pk_fma_f16 %0, %1, %2, %3 op_sel:[0,1,0] op_sel_hi:[1,0,1]"
        : "=v"(d) : "v"(su), "v"(pu), "v"(tu));
    return U2H(d);
}

#define LOADSC(L, Q) { uint2 w_ = wtab[(L) * NQ + (Q)];                 \
    sp_ = U2H(w_.x); cc_ = U2H(w_.y); }

// Butterfly on register bit QBIT: a0' = cc*a0 + sp*J(a1), a1' = cc*a1 + sp*J(a0)
#define RXQ(ARR, QBIT) { _Pragma("unroll")                              \
    for (int o = 0; o < APT; ++o) {                                     \
        if (o & (1 << (QBIT))) continue;                                \
        const int o1_ = o | (1 << (QBIT));                              \
        __half2 m0_ = __hmul2(cc_, ARR[o]);                             \
        __half2 m1_ = __hmul2(cc_, ARR[o1_]);                           \
        __half2 p0_ = ARR[o1_], p1_ = ARR[o];                           \
        ARR[o]   = fma_sw(sp_, p0_, m0_);                               \
        ARR[o1_] = fma_sw(sp_, p1_, m1_); } }

#define RXD(ARR, DPPM) { _Pragma("unroll")                              \
    for (int o = 0; o < APT; ++o) {                                     \
        __half2 p_ = DPPM(ARR[o]);                                      \
        ARR[o] = fma_sw(sp_, p_, __hmul2(cc_, ARR[o])); } }

#define RXLOW(ARR, L)  { __half2 sp_, cc_;                              \
    LOADSC(L,0) RXQ(ARR,0) LOADSC(L,1) RXQ(ARR,1) LOADSC(L,2) RXQ(ARR,2)\
    LOADSC(L,3) RXQ(ARR,3) LOADSC(L,4) RXQ(ARR,4)                       \
    LOADSC(L,5) RXD(ARR,DPP1) LOADSC(L,6) RXD(ARR,DPP2) }
#define RXHIGH(ARR, L) { __half2 sp_, cc_;                              \
    LOADSC(L,7) RXQ(ARR,0) LOADSC(L,8) RXQ(ARR,1) LOADSC(L,9) RXQ(ARR,2)\
    LOADSC(L,10) RXQ(ARR,3) LOADSC(L,11) RXQ(ARR,4)                     \
    LOADSC(L,12) RXD(ARR,DPP1) LOADSC(L,13) RXD(ARR,DPP2) }

// o-part address constants (k = pair index, compile-time in unrolled loops)
#define K0(k) ((k)&1)
#define K1(k) (((k)>>1)&1)
#define K2(k) (((k)>>2)&1)
#define K3(k) (((k)>>3)&1)
#define GW1K(k) ((K0(k)<<3)|(K1(k)<<4)|(K2(k)<<6)|(K3(k)<<7))
#define GR1K(k) ((K0(k)<<3)|(K1(k)<<4)|(K2(k)<<8)|(K3(k)<<9)|(K0(k)<<12)|(K1(k)<<13))
#define GW2K(k) ((K0(k)<<1)|(K1(k)<<2)|(K2(k)<<3)|(K3(k)<<4)|(K0(k)<<10)|(K1(k)<<11)|(K2(k)<<12)|(K3(k)<<13))
#define GR2K(k) (((K0(k)^K1(k))<<3)|((K1(k)^K2(k))<<4)|((K2(k)^K3(k))<<7)|(K3(k)<<8))

#define WS1(ARR, BUF) { _Pragma("unroll") for (int k = 0; k < 16; ++k)  \
    *reinterpret_cast<uint2*>((BUF) + (CW1x ^ GW1K(k))) =               \
        make_uint2(H2U(ARR[2*k]), H2U(ARR[2*k+1])); }
#define RS1(ARR, BUF) { _Pragma("unroll") for (int k = 0; k < 16; ++k) {\
    const __half2* rp_ = (BUF) + (CR1x ^ GR1K(k));                      \
    ARR[2*k] = rp_[0]; ARR[2*k+1] = rp_[32]; } }
#define WS2(ARR, BUF) { _Pragma("unroll") for (int k = 0; k < 16; ++k)  \
    *reinterpret_cast<uint2*>((BUF) + (CW2x ^ GW2K(k))) =               \
        make_uint2(H2U(ARR[2*k]), H2U(ARR[2*k+1])); }
#define RS2(ARR, BUF) { _Pragma("unroll") for (int k = 0; k < 16; ++k) {\
    const __half2* rp_ = (BUF) + (CR2x ^ GR2K(k));                      \
    ARR[2*k]   = rp_[(K0(k))<<6];                                       \
    ARR[2*k+1] = rp_[32 | ((K0(k)^1)<<6)]; } }

// Product-state encoding fused with layer-0 CNOT perm, into P0 registers.
#define ENCODE(ARR, TBL) {                                              \
    float base_ = 1.0f;                                                 \
    _Pragma("unroll") for (int q = 6; q < NQ; ++q) {                    \
        float2 f_ = (TBL)[q];                                           \
        base_ *= ((Tm >> (q - 5)) & 1) ? f_.x : f_.y; }                 \
    float2 f5_ = (TBL)[5];                                              \
    float g5a_ = (t & 1) ? f5_.x : f5_.y;                               \
    float g5b_ = (t & 1) ? f5_.y : f5_.x;                               \
    float2 f0_ = (TBL)[0], f1_ = (TBL)[1], f2_ = (TBL)[2],              \
           f3_ = (TBL)[3], f4_ = (TBL)[4];                              \
    _Pragma("unroll") for (int o = 0; o < APT; ++o) {                   \
        const int op_ = o ^ (o << 1);                                   \
        float v_ = base_ * ((op_ & 32) ? g5b_ : g5a_);                  \
        v_ *= (op_ & 1)  ? f0_.x : f0_.y;                               \
        v_ *= (op_ & 2)  ? f1_.x : f1_.y;                               \
        v_ *= (op_ & 4)  ? f2_.x : f2_.y;                               \
        v_ *= (op_ & 8)  ? f3_.x : f3_.y;                               \
        v_ *= (op_ & 16) ? f4_.x : f4_.y;                               \
        ARR[o] = __floats2half2_rn(v_, 0.0f); } }

// Z-expectation partials from P1 layout -> RED[wave*12 + 0..11]  (v9-proven)
#define EXPECT(ARR, RED) {                                              \
    float ptot = 0.f, Sq[5] = {0, 0, 0, 0, 0};                          \
    _Pragma("unroll") for (int o = 0; o < APT; ++o) {                   \
        float2 f_ = __half22float2(ARR[o]);                             \
        float p_ = f_.x * f_.x + f_.y * f_.y;                           \
        ptot += p_;                                                     \
        _Pragma("unroll") for (int m = 0; m < 5; ++m)                   \
            Sq[m] += ((o >> m) & 1) ? -p_ : p_; }                       \
    float accL[6];                                                      \
    _Pragma("unroll") for (int k = 0; k < 6; ++k) accL[k] = ptot;       \
    _Pragma("unroll") for (int k = 0; k < 6; ++k) {                     \
        const int m_ = 1 << k;                                          \
        _Pragma("unroll") for (int j = 0; j < 6; ++j) {                 \
            float pr_ = __shfl_xor(accL[j], m_, 64);                    \
            if (j == k) accL[j] = ((lane >> k) & 1) ? (pr_ - accL[j])   \
                                                    : (accL[j] - pr_);  \
            else accL[j] += pr_; }                                      \
        ptot += __shfl_xor(ptot, m_, 64);                               \
        _Pragma("unroll") for (int j2 = 0; j2 < 5; ++j2)                \
            Sq[j2] += __shfl_xor(Sq[j2], m_, 64); }                     \
    if (lane == 0) {                                                    \
        (RED)[wv * 12 + 0] = ptot;                                      \
        _Pragma("unroll") for (int k = 0; k < 6; ++k) (RED)[wv * 12 + 1 + k] = accL[k]; \
        _Pragma("unroll") for (int m2 = 0; m2 < 5; ++m2) (RED)[wv * 12 + 7 + m2] = Sq[m2]; } }

__global__ __launch_bounds__(NT, 2)
void vqc_kernel(const float* __restrict__ inputs,
                const float* __restrict__ weights,
                float* __restrict__ out)
{
    extern __shared__ __half2 lds[];   // buf0 | buf1 | wtab | itab | redA | redB
    const int t    = threadIdx.x;
    const int b    = blockIdx.x;
    const int lane = t & 63;
    const int wv   = t >> 6;
    const int sA   = 2 * b, sB = 2 * b + 1;
    const int Tm   = (t ^ (t << 1)) & 0x3FF;

    __half2* buf0 = lds;
    __half2* buf1 = lds + DIM;
    uint2*   wtab = reinterpret_cast<uint2*>(lds + 2 * DIM);   // 56
    float2*  itab = reinterpret_cast<float2*>(wtab + 56);      // 28
    float*   redA = reinterpret_cast<float*>(itab + 28);       // 96
    float*   redB = redA + 96;                                 // 96

    // Thread bits
    const int t0 = t & 1, t1 = (t >> 1) & 1, t2 = (t >> 2) & 1, t3 = (t >> 3) & 1,
              t4 = (t >> 4) & 1, t5 = (t >> 5) & 1, t6 = (t >> 6) & 1,
              t7 = (t >> 7) & 1, t8 = (t >> 8) & 1;

    // Per-sweep thread-constant address bases (maps in header, spot-verified)
    const int CW1x = ((t0^t7)<<1)|((t1^t8)<<2)|(t3<<3)|(t4<<4)|(t2<<5)
                   | (t5<<8)|(t6<<9)|(t0<<10)|(t1<<11)|(t3<<12)|(t4<<13);
    const int CR1x = t2 | ((t7^t0)<<1)|((t8^t1)<<2)|(t3<<3)|(t4<<4)
                   | (t5<<6)|(t6<<7)|(t7<<10)|(t8<<11);
    const int CW2x = (t0<<1)|(t1<<2)|(t4<<3)|(t5<<4)|(t2<<5)|(t3<<6)
                   | (t6<<7)|(t7<<8)|(t8<<9);
    const int CR2x = (t2^t1) | ((t7^t6^t3^t2)<<1) | ((t8^t7^t4^t3)<<2)
                   | ((t5^t4)<<3) | ((t6^t5)<<4) | (t0<<8) | ((t1^t0)<<9)
                   | ((t3^t2)<<10) | ((t4^t3)<<11) | ((t5^t4)<<12) | ((t6^t5)<<13);

    // Sincos tables: wave0 does weights (sp,cc packed), wave1 does inputs.
    if (t < NL * NQ) {
        float s_, c_;
        __sincosf(0.5f * weights[t], &s_, &c_);
        wtab[t] = make_uint2(H2U(__floats2half2_rn(s_, -s_)), H2U(__float2half2_rn(c_)));
    }
    if (t >= 64 && t < 64 + 2 * NQ) {
        int i_ = t - 64;
        int si_ = (i_ >= NQ) ? 1 : 0;
        float s_, c_;
        __sincosf(0.5f * inputs[(sA + si_) * NQ + (i_ - NQ * si_)], &s_, &c_);
        itab[i_] = make_float2(s_, c_);
    }
    __syncthreads();

    __half2 aA[APT], aB[APT];

    // p0
    ENCODE(aA, itab);       RXLOW(aA, 0);    WS1(aA, buf0);  __syncthreads();
    // p1
    RS1(aA, buf0);  ENCODE(aB, itab + NQ); RXLOW(aB, 0); WS1(aB, buf1); __syncthreads();
    // p2
    RS1(aB, buf1);  RXHIGH(aA, 0);  WS2(aA, buf0);  __syncthreads();
    // p3
    RS2(aA, buf0);  RXHIGH(aB, 0);  WS2(aB, buf1);  __syncthreads();

#pragma unroll 1
    for (int l = 1; l < NL - 1; ++l) {
        RS2(aB, buf1);  RXLOW(aA, l);   WS1(aA, buf0);  __syncthreads();
        RS1(aA, buf0);  RXLOW(aB, l);   WS1(aB, buf1);  __syncthreads();
        RS1(aB, buf1);  RXHIGH(aA, l);  WS2(aA, buf0);  __syncthreads();
        RS2(aA, buf0);  RXHIGH(aB, l);  WS2(aB, buf1);  __syncthreads();
    }
    // tail: layer 3 (no dead writes)
    RS2(aB, buf1);  RXLOW(aA, 3);   WS1(aA, buf0);  __syncthreads();
    RS1(aA, buf0);  RXLOW(aB, 3);   WS1(aB, buf1);  __syncthreads();
    RS1(aB, buf1);  RXHIGH(aA, 3);  RXHIGH(aB, 3);

    EXPECT(aA, redA);
    EXPECT(aB, redB);
    __syncthreads();

    // Cross-wave combine. P1: lane2-5 = q0-3, wave bits = q4-6, o = q7-11,
    // lane0,1 = q12,13.
    if (t < NQ) {
        float accA = 0.f, accB = 0.f;
#pragma unroll 1
        for (int w = 0; w < 8; ++w) {
            float vA, vB;
            if (t < 4)       { vA = redA[w * 12 + 3 + t];        vB = redB[w * 12 + 3 + t]; }
            else if (t < 7)  { vA = redA[w * 12];                vB = redB[w * 12];
                               if ((w >> (t - 4)) & 1) { vA = -vA; vB = -vB; } }
            else if (t < 12) { vA = redA[w * 12 + 7 + (t - 7)];  vB = redB[w * 12 + 7 + (t - 7)]; }
            else             { vA = redA[w * 12 + 1 + (t - 12)]; vB = redB[w * 12 + 1 + (t - 12)]; }
            accA += vA; accB += vB;
        }
        out[sA * NQ + t] = accA;
        out[sB * NQ + t] = accB;
    }
}

extern "C" void kernel_launch(void* const* d_in, const int* in_sizes, int n_in,
                              void* d_out, int out_size, void* d_ws, size_t ws_size,
                              hipStream_t stream)
{
    const float* inputs  = (const float*)d_in[0];
    const float* weights = (const float*)d_in[1];
    float* out = (float*)d_out;

    const int Bn = in_sizes[0] / NQ;   // 1024
    const size_t shmem = 2 * DIM * sizeof(__half2)
                       + 56 * sizeof(uint2) + 28 * sizeof(float2)
                       + 192 * sizeof(float);
    vqc_kernel<<<dim3(Bn / 2), dim3(NT), shmem, stream>>>(inputs, weights, out);
}

// Round 11
// 98.252 us; speedup vs baseline: 1.7516x; 1.0111x over previous
//
#include <hip/hip_runtime.h>
#include <hip/hip_fp16.h>

// VQC statevector simulator, v11 = v10 with conflict-free-by-construction
// sweep address maps. v10's maps measured 8.4M bank-conflict cycles (~13us);
// v11 rebuilds both LDS image maps so that:
//  - WRITES are contiguous ds_write_b64 streams: pair bit (o0) -> addr bit0,
//    lane bits t0-t5 -> addr bits 1-6 => each wave writes 128 consecutive
//    dwords (XOR terms from o/waves only permute within or shift outside the
//    block) = 4 dwords/bank streaming minimum, zero extra cycles.
//  - READS are rank-5 b32: the 6 read-lane canonical bits have XOR-mixed
//    images whose bank-bit (a0-a4) projection has rank 5 => exactly 2
//    lanes/bank (free, m136).
// Both maps bijective (triangular via fresh high bits); write evenness holds
// (no a0 component outside the pair bit); 4 canonical indices spot-checked
// write->read end-to-end, incl. the S2 perm telescoping (t=508 case -> addr 1).
//
// Windows (canonical bit q = qubit q), t = 9 thread bits t0..t8:
//  P0: q0-4 = reg o; q5,q6 = t0,t1 (DPP); q7-13 = t2..t8.
//  P1: q7-11 = reg o; q12,q13 = t0,t1 (DPP); q0-6 = t2..t8.
// Per layer/sample: RXLOW(P0) -> S1(P0->P1) -> RXHIGH(P1) -> S2(P1->P0 with
// CNOT-chain perm src=(n^(n<<1))&mask folded into the read). Layer-0 perm
// fused into encoding. Phase schedule, RX (op_sel pk_fma), ENCODE, EXPECT
// identical to v10 (passed, absmax 7.8e-3).
//
// Map A (S1):  c0->1  c1->130 c2->260 c3->520 c4->4096 c5..c10->2,4,8,16,32,64
//              c11->8192 c12->1040 c13->2048
// Map B (S2):  c0->8 c1->16 c2->32 c3->64 c4->8192 c5->128 c6->258 c7->1
//              c8->516 c9->1036 c10->2076 c11->4124 c12->2 c13->4

typedef unsigned int u32;

constexpr int NQ  = 14;
constexpr int DIM = 1 << NQ;     // 16384
constexpr int NT  = 512;         // 8 waves
constexpr int APT = DIM / NT;    // 32
constexpr int NL  = 4;

#define H2U(v) __builtin_bit_cast(u32, v)
#define U2H(v) __builtin_bit_cast(__half2, v)
// quad_perm lane^1 = 0xB1, lane^2 = 0x4E
#define DPP1(v) U2H((u32)__builtin_amdgcn_mov_dpp((int)H2U(v), 0xB1, 0xF, 0xF, true))
#define DPP2(v) U2H((u32)__builtin_amdgcn_mov_dpp((int)H2U(v), 0x4E, 0xF, 0xF, true))

// d.lo = s.lo*p.hi + t.lo ; d.hi = s.hi*p.lo + t.hi  (swap fused via op_sel)
static __device__ __forceinline__ __half2 fma_sw(__half2 s, __half2 p, __half2 t) {
    u32 d, su = H2U(s), pu = H2U(p), tu = H2U(t);
    asm("v_pk_fma_f16 %0, %1, %2, %3 op_sel:[0,1,0] op_sel_hi:[1,0,1]"
        : "=v"(d) : "v"(su), "v"(pu), "v"(tu));
    return U2H(d);
}

#define LOADSC(L, Q) { uint2 w_ = wtab[(L) * NQ + (Q)];                 \
    sp_ = U2H(w_.x); cc_ = U2H(w_.y); }

#define RXQ(ARR, QBIT) { _Pragma("unroll")                              \
    for (int o = 0; o < APT; ++o) {                                     \
        if (o & (1 << (QBIT))) continue;                                \
        const int o1_ = o | (1 << (QBIT));                              \
        __half2 m0_ = __hmul2(cc_, ARR[o]);                             \
        __half2 m1_ = __hmul2(cc_, ARR[o1_]);                           \
        __half2 p0_ = ARR[o1_], p1_ = ARR[o];                           \
        ARR[o]   = fma_sw(sp_, p0_, m0_);                               \
        ARR[o1_] = fma_sw(sp_, p1_, m1_); } }

#define RXD(ARR, DPPM) { _Pragma("unroll")                              \
    for (int o = 0; o < APT; ++o) {                                     \
        __half2 p_ = DPPM(ARR[o]);                                      \
        ARR[o] = fma_sw(sp_, p_, __hmul2(cc_, ARR[o])); } }

#define RXLOW(ARR, L)  { __half2 sp_, cc_;                              \
    LOADSC(L,0) RXQ(ARR,0) LOADSC(L,1) RXQ(ARR,1) LOADSC(L,2) RXQ(ARR,2)\
    LOADSC(L,3) RXQ(ARR,3) LOADSC(L,4) RXQ(ARR,4)                       \
    LOADSC(L,5) RXD(ARR,DPP1) LOADSC(L,6) RXD(ARR,DPP2) }
#define RXHIGH(ARR, L) { __half2 sp_, cc_;                              \
    LOADSC(L,7) RXQ(ARR,0) LOADSC(L,8) RXQ(ARR,1) LOADSC(L,9) RXQ(ARR,2)\
    LOADSC(L,10) RXQ(ARR,3) LOADSC(L,11) RXQ(ARR,4)                     \
    LOADSC(L,12) RXD(ARR,DPP1) LOADSC(L,13) RXD(ARR,DPP2) }

// ---- sweep o-offset tables (compile-time constants per unrolled index) ----
#define OW1K(k) ((((k)&1)?130:0) | (((k)&2)?260:0) | (((k)&4)?520:0) | (((k)&8)?4096:0))
#define OR1(o)  ((((o)&15)<<3) | (((o)>>4)<<13))
#define OW2K(k) ((((k)&1)?516:0) ^ (((k)&2)?1036:0) ^ (((k)&4)?2076:0) ^ (((k)&8)?4124:0))
#define OR2(o)  ((((o)&1)?24:0) ^ (((o)&2)?48:0) ^ (((o)&4)?96:0) ^ (((o)&8)?8256:0) ^ (((o)&16)?8320:0))

#define WS1(ARR, BUF) { _Pragma("unroll") for (int k = 0; k < 16; ++k)  \
    *reinterpret_cast<uint2*>((BUF) + (CW1 ^ OW1K(k))) =                \
        make_uint2(H2U(ARR[2*k]), H2U(ARR[2*k+1])); }
#define RS1(ARR, BUF) { _Pragma("unroll") for (int o = 0; o < APT; ++o) \
    ARR[o] = (BUF)[CR1 ^ OR1(o)]; }
#define WS2(ARR, BUF) { _Pragma("unroll") for (int k = 0; k < 16; ++k)  \
    *reinterpret_cast<uint2*>((BUF) + (CW2 ^ OW2K(k))) =                \
        make_uint2(H2U(ARR[2*k]), H2U(ARR[2*k+1])); }
#define RS2(ARR, BUF) { _Pragma("unroll") for (int o = 0; o < APT; ++o) \
    ARR[o] = (BUF)[CR2 ^ OR2(o)]; }

// Product-state encoding fused with layer-0 CNOT perm, into P0 registers.
#define ENCODE(ARR, TBL) {                                              \
    float base_ = 1.0f;                                                 \
    _Pragma("unroll") for (int q = 6; q < NQ; ++q) {                    \
        float2 f_ = (TBL)[q];                                           \
        base_ *= ((Tm >> (q - 5)) & 1) ? f_.x : f_.y; }                 \
    float2 f5_ = (TBL)[5];                                              \
    float g5a_ = (t & 1) ? f5_.x : f5_.y;                               \
    float g5b_ = (t & 1) ? f5_.y : f5_.x;                               \
    float2 f0_ = (TBL)[0], f1_ = (TBL)[1], f2_ = (TBL)[2],              \
           f3_ = (TBL)[3], f4_ = (TBL)[4];                              \
    _Pragma("unroll") for (int o = 0; o < APT; ++o) {                   \
        const int op_ = o ^ (o << 1);                                   \
        float v_ = base_ * ((op_ & 32) ? g5b_ : g5a_);                  \
        v_ *= (op_ & 1)  ? f0_.x : f0_.y;                               \
        v_ *= (op_ & 2)  ? f1_.x : f1_.y;                               \
        v_ *= (op_ & 4)  ? f2_.x : f2_.y;                               \
        v_ *= (op_ & 8)  ? f3_.x : f3_.y;                               \
        v_ *= (op_ & 16) ? f4_.x : f4_.y;                               \
        ARR[o] = __floats2half2_rn(v_, 0.0f); } }

// Z-expectation partials from P1 layout -> RED[wave*12 + 0..11]  (v9/v10-proven)
#define EXPECT(ARR, RED) {                                              \
    float ptot = 0.f, Sq[5] = {0, 0, 0, 0, 0};                          \
    _Pragma("unroll") for (int o = 0; o < APT; ++o) {                   \
        float2 f_ = __half22float2(ARR[o]);                             \
        float p_ = f_.x * f_.x + f_.y * f_.y;                           \
        ptot += p_;                                                     \
        _Pragma("unroll") for (int m = 0; m < 5; ++m)                   \
            Sq[m] += ((o >> m) & 1) ? -p_ : p_; }                       \
    float accL[6];                                                      \
    _Pragma("unroll") for (int k = 0; k < 6; ++k) accL[k] = ptot;       \
    _Pragma("unroll") for (int k = 0; k < 6; ++k) {                     \
        const int m_ = 1 << k;                                          \
        _Pragma("unroll") for (int j = 0; j < 6; ++j) {                 \
            float pr_ = __shfl_xor(accL[j], m_, 64);                    \
            if (j == k) accL[j] = ((lane >> k) & 1) ? (pr_ - accL[j])   \
                                                    : (accL[j] - pr_);  \
            else accL[j] += pr_; }                                      \
        ptot += __shfl_xor(ptot, m_, 64);                               \
        _Pragma("unroll") for (int j2 = 0; j2 < 5; ++j2)                \
            Sq[j2] += __shfl_xor(Sq[j2], m_, 64); }                     \
    if (lane == 0) {                                                    \
        (RED)[wv * 12 + 0] = ptot;                                      \
        _Pragma("unroll") for (int k = 0; k < 6; ++k) (RED)[wv * 12 + 1 + k] = accL[k]; \
        _Pragma("unroll") for (int m2 = 0; m2 < 5; ++m2) (RED)[wv * 12 + 7 + m2] = Sq[m2]; } }

__global__ __launch_bounds__(NT, 2)
void vqc_kernel(const float* __restrict__ inputs,
                const float* __restrict__ weights,
                float* __restrict__ out)
{
    extern __shared__ __half2 lds[];   // buf0 | buf1 | wtab | itab | redA | redB
    const int t    = threadIdx.x;
    const int b    = blockIdx.x;
    const int lane = t & 63;
    const int wv   = t >> 6;
    const int sA   = 2 * b, sB = 2 * b + 1;
    const int Tm   = (t ^ (t << 1)) & 0x3FF;

    __half2* buf0 = lds;
    __half2* buf1 = lds + DIM;
    uint2*   wtab = reinterpret_cast<uint2*>(lds + 2 * DIM);   // 56
    float2*  itab = reinterpret_cast<float2*>(wtab + 56);      // 28
    float*   redA = reinterpret_cast<float*>(itab + 28);       // 96
    float*   redB = redA + 96;                                 // 96

    const int t0 = t & 1, t1 = (t >> 1) & 1, t2 = (t >> 2) & 1, t3 = (t >> 3) & 1,
              t4 = (t >> 4) & 1, t5 = (t >> 5) & 1, t6 = (t >> 6) & 1,
              t7 = (t >> 7) & 1, t8 = (t >> 8) & 1;

    // Thread-constant address bases (maps A,B in header; XOR-accumulated).
    const int CW1 = ((t & 63) << 1) ^ (t6 ? 8192 : 0) ^ (t7 ? 1040 : 0) ^ (t8 ? 2048 : 0);
    const int CR1 = (t0 ? 1040 : 0) ^ (t1 ? 2048 : 0) ^ (t2 ? 1 : 0) ^ (t3 ? 130 : 0)
                  ^ (t4 ? 260 : 0) ^ (t5 ? 520 : 0) ^ (t6 ? 4096 : 0)
                  ^ (t7 ? 2 : 0) ^ (t8 ? 4 : 0);
    const int CW2 = ((t & 63) << 1) ^ (t6 ? 8192 : 0) ^ (t7 ? 128 : 0) ^ (t8 ? 258 : 0);
    const int CR2 = (t0 ? 386 : 0) ^ (t1 ? 259 : 0) ^ (t2 ? 517 : 0) ^ (t3 ? 1544 : 0)
                  ^ (t4 ? 3088 : 0) ^ (t5 ? 6144 : 0) ^ (t6 ? 4126 : 0)
                  ^ (t7 ? 6 : 0) ^ (t8 ? 4 : 0);

    // Sincos tables: wave0 does weights (sp,cc packed), wave1 does inputs.
    if (t < NL * NQ) {
        float s_, c_;
        __sincosf(0.5f * weights[t], &s_, &c_);
        wtab[t] = make_uint2(H2U(__floats2half2_rn(s_, -s_)), H2U(__float2half2_rn(c_)));
    }
    if (t >= 64 && t < 64 + 2 * NQ) {
        int i_ = t - 64;
        int si_ = (i_ >= NQ) ? 1 : 0;
        float s_, c_;
        __sincosf(0.5f * inputs[(sA + si_) * NQ + (i_ - NQ * si_)], &s_, &c_);
        itab[i_] = make_float2(s_, c_);
    }
    __syncthreads();

    __half2 aA[APT], aB[APT];

    // p0
    ENCODE(aA, itab);       RXLOW(aA, 0);    WS1(aA, buf0);  __syncthreads();
    // p1
    RS1(aA, buf0);  ENCODE(aB, itab + NQ); RXLOW(aB, 0); WS1(aB, buf1); __syncthreads();
    // p2
    RS1(aB, buf1);  RXHIGH(aA, 0);  WS2(aA, buf0);  __syncthreads();
    // p3
    RS2(aA, buf0);  RXHIGH(aB, 0);  WS2(aB, buf1);  __syncthreads();

#pragma unroll 1
    for (int l = 1; l < NL - 1; ++l) {
        RS2(aB, buf1);  RXLOW(aA, l);   WS1(aA, buf0);  __syncthreads();
        RS1(aA, buf0);  RXLOW(aB, l);   WS1(aB, buf1);  __syncthreads();
        RS1(aB, buf1);  RXHIGH(aA, l);  WS2(aA, buf0);  __syncthreads();
        RS2(aA, buf0);  RXHIGH(aB, l);  WS2(aB, buf1);  __syncthreads();
    }
    // tail: layer 3 (no dead writes)
    RS2(aB, buf1);  RXLOW(aA, 3);   WS1(aA, buf0);  __syncthreads();
    RS1(aA, buf0);  RXLOW(aB, 3);   WS1(aB, buf1);  __syncthreads();
    RS1(aB, buf1);  RXHIGH(aA, 3);  RXHIGH(aB, 3);

    EXPECT(aA, redA);
    EXPECT(aB, redB);
    __syncthreads();

    // Cross-wave combine. P1: lane2-5 = q0-3, wave bits = q4-6, o = q7-11,
    // lane0,1 = q12,13.
    if (t < NQ) {
        float accA = 0.f, accB = 0.f;
#pragma unroll 1
        for (int w = 0; w < 8; ++w) {
            float vA, vB;
            if (t < 4)       { vA = redA[w * 12 + 3 + t];        vB = redB[w * 12 + 3 + t]; }
            else if (t < 7)  { vA = redA[w * 12];                vB = redB[w * 12];
                               if ((w >> (t - 4)) & 1) { vA = -vA; vB = -vB; } }
            else if (t < 12) { vA = redA[w * 12 + 7 + (t - 7)];  vB = redB[w * 12 + 7 + (t - 7)]; }
            else             { vA = redA[w * 12 + 1 + (t - 12)]; vB = redB[w * 12 + 1 + (t - 12)]; }
            accA += vA; accB += vB;
        }
        out[sA * NQ + t] = accA;
        out[sB * NQ + t] = accB;
    }
}

extern "C" void kernel_launch(void* const* d_in, const int* in_sizes, int n_in,
                              void* d_out, int out_size, void* d_ws, size_t ws_size,
                              hipStream_t stream)
{
    const float* inputs  = (const float*)d_in[0];
    const float* weights = (const float*)d_in[1];
    float* out = (float*)d_out;

    const int Bn = in_sizes[0] / NQ;   // 1024
    const size_t shmem = 2 * DIM * sizeof(__half2)
                       + 56 * sizeof(uint2) + 28 * sizeof(float2)
                       + 192 * sizeof(float);
    vqc_kernel<<<dim3(Bn / 2), dim3(NT), shmem, stream>>>(inputs, weights, out);
}

// Round 12
// 94.786 us; speedup vs baseline: 1.8156x; 1.0366x over previous
//
#include <hip/hip_runtime.h>
#include <hip/hip_fp16.h>

// VQC statevector simulator, v12 = v11 + pipeline de-serialization.
// v11 counters: conflicts 8.4M->2.1M but dur flat (98us) -> conflicts were
// off the critical path. Two real serializers (LDS completes IN-ORDER):
//  (1) per-butterfly wtab ds_read issued AFTER the 32 RS reads -> waiting for
//      the coefficient drains the whole RS queue; RS||RX overlap never happens.
//  (2) sweep writes depend on RX output -> 16 b64 writes + lgkmcnt(0) + bar
//      exposed after every RX block.
// v12: (a) coefficients preloaded into SGPRs (ds_read_b64 + readfirstlane) at
// the END of the previous phase, where the barrier pays lgkmcnt(0) anyway ->
// RX has zero LDS deps, RS reads trickle in under compute. (b) sweep write
// fused into the final DPP butterfly loop (pair written as finalized) ->
// write tail hides under VALU. (c) EXPECT xor-1/2 levels via DPP quad_perm
// (the residual 2^21 conflicts = bpermute crossbar).
//
// Maps, windows, schedule, arithmetic identical to v11 (passed, absmax 7.8e-3):
//  P0: q0-4 = reg o; q5,q6 = t0,t1 (DPP); q7-13 = t2..t8.
//  P1: q7-11 = reg o; q12,q13 = t0,t1 (DPP); q0-6 = t2..t8.
//  RXLOW(P0) -> S1(P0->P1) -> RXHIGH(P1) -> S2(P1->P0, CNOT perm in read).
//  Map A (S1): c0->1 c1->130 c2->260 c3->520 c4->4096 c5..c10->2..64
//              c11->8192 c12->1040 c13->2048
//  Map B (S2): c0->8 c1->16 c2->32 c3->64 c4->8192 c5->128 c6->258 c7->1
//              c8->516 c9->1036 c10->2076 c11->4124 c12->2 c13->4

typedef unsigned int u32;

constexpr int NQ  = 14;
constexpr int DIM = 1 << NQ;     // 16384
constexpr int NT  = 512;         // 8 waves
constexpr int APT = DIM / NT;    // 32
constexpr int NL  = 4;

#define H2U(v) __builtin_bit_cast(u32, v)
#define U2H(v) __builtin_bit_cast(__half2, v)
// quad_perm lane^1 = 0xB1, lane^2 = 0x4E
#define DPP1(v) U2H((u32)__builtin_amdgcn_mov_dpp((int)H2U(v), 0xB1, 0xF, 0xF, true))
#define DPP2(v) U2H((u32)__builtin_amdgcn_mov_dpp((int)H2U(v), 0x4E, 0xF, 0xF, true))
#define DPPF1(v) __builtin_bit_cast(float, (u32)__builtin_amdgcn_mov_dpp((int)__builtin_bit_cast(u32, v), 0xB1, 0xF, 0xF, true))
#define DPPF2(v) __builtin_bit_cast(float, (u32)__builtin_amdgcn_mov_dpp((int)__builtin_bit_cast(u32, v), 0x4E, 0xF, 0xF, true))
// EXPECT cross-lane: levels 0,1 via DPP (VALU), rest via shfl (LDS crossbar)
#define SHX(V, K) ((K) == 0 ? DPPF1(V) : (K) == 1 ? DPPF2(V) : __shfl_xor((V), 1 << (K), 64))

// d.lo = s.lo*p.hi + t.lo ; d.hi = s.hi*p.lo + t.hi  (swap fused via op_sel)
static __device__ __forceinline__ __half2 fma_sw(__half2 s, __half2 p, __half2 t) {
    u32 d, su = H2U(s), pu = H2U(p), tu = H2U(t);
    asm("v_pk_fma_f16 %0, %1, %2, %3 op_sel:[0,1,0] op_sel_hi:[1,0,1]"
        : "=v"(d) : "v"(su), "v"(pu), "v"(tu));
    return U2H(d);
}

// Preload 7 qubits' (sp,cc) of layer L starting at qubit Q0 into SGPR arrays.
// Issued at the END of the previous phase: the pre-barrier lgkmcnt(0) covers
// the wait, so the next phase's RX has no LDS dependency.
#define PRELOADW(L, Q0) { _Pragma("unroll")                             \
    for (int i_ = 0; i_ < 7; ++i_) {                                    \
        uint2 w_ = wtab[(L) * NQ + (Q0) + i_];                          \
        sw[i_] = __builtin_amdgcn_readfirstlane((int)w_.x);             \
        cw[i_] = __builtin_amdgcn_readfirstlane((int)w_.y); } }

#define RXQs(ARR, QBIT, I) {                                            \
    const __half2 sp_ = U2H((u32)sw[I]), cc_ = U2H((u32)cw[I]);         \
    _Pragma("unroll")                                                   \
    for (int o = 0; o < APT; ++o) {                                     \
        if (o & (1 << (QBIT))) continue;                                \
        const int o1_ = o | (1 << (QBIT));                              \
        __half2 m0_ = __hmul2(cc_, ARR[o]);                             \
        __half2 m1_ = __hmul2(cc_, ARR[o1_]);                           \
        __half2 p0_ = ARR[o1_], p1_ = ARR[o];                           \
        ARR[o]   = fma_sw(sp_, p0_, m0_);                               \
        ARR[o1_] = fma_sw(sp_, p1_, m1_); } }

#define RXDs(ARR, DPPM, I) {                                            \
    const __half2 sp_ = U2H((u32)sw[I]), cc_ = U2H((u32)cw[I]);         \
    _Pragma("unroll")                                                   \
    for (int o = 0; o < APT; ++o) {                                     \
        __half2 p_ = DPPM(ARR[o]);                                      \
        ARR[o] = fma_sw(sp_, p_, __hmul2(cc_, ARR[o])); } }

// Final DPP butterfly with the sweep write fused per pair (write tail hidden).
#define RXD_W(ARR, DPPM, I, BUF, WADDRK) {                              \
    const __half2 sp_ = U2H((u32)sw[I]), cc_ = U2H((u32)cw[I]);         \
    _Pragma("unroll")                                                   \
    for (int k = 0; k < 16; ++k) {                                      \
        __half2 p0_ = DPPM(ARR[2*k]);                                   \
        ARR[2*k]   = fma_sw(sp_, p0_, __hmul2(cc_, ARR[2*k]));          \
        __half2 p1_ = DPPM(ARR[2*k+1]);                                 \
        ARR[2*k+1] = fma_sw(sp_, p1_, __hmul2(cc_, ARR[2*k+1]));        \
        *reinterpret_cast<uint2*>((BUF) + (WADDRK)) =                   \
            make_uint2(H2U(ARR[2*k]), H2U(ARR[2*k+1])); } }

// ---- sweep o-offset tables (compile-time per unrolled index), from v11 ----
#define OW1K(k) ((((k)&1)?130:0) | (((k)&2)?260:0) | (((k)&4)?520:0) | (((k)&8)?4096:0))
#define OR1(o)  ((((o)&15)<<3) | (((o)>>4)<<13))
#define OW2K(k) ((((k)&1)?516:0) ^ (((k)&2)?1036:0) ^ (((k)&4)?2076:0) ^ (((k)&8)?4124:0))
#define OR2(o)  ((((o)&1)?24:0) ^ (((o)&2)?48:0) ^ (((o)&4)?96:0) ^ (((o)&8)?8256:0) ^ (((o)&16)?8320:0))

#define RS1(ARR, BUF) { _Pragma("unroll") for (int o = 0; o < APT; ++o) \
    ARR[o] = (BUF)[CR1 ^ OR1(o)]; }
#define RS2(ARR, BUF) { _Pragma("unroll") for (int o = 0; o < APT; ++o) \
    ARR[o] = (BUF)[CR2 ^ OR2(o)]; }

// 7-qubit RX block with fused write (RXLOW -> S1 write addr; RXHIGH -> S2).
#define RXLOW_F(ARR, BUF)  { RXQs(ARR,0,0) RXQs(ARR,1,1) RXQs(ARR,2,2)  \
    RXQs(ARR,3,3) RXQs(ARR,4,4) RXDs(ARR,DPP1,5)                        \
    RXD_W(ARR,DPP2,6,BUF,(CW1 ^ OW1K(k))) }
#define RXHIGH_F(ARR, BUF) { RXQs(ARR,0,0) RXQs(ARR,1,1) RXQs(ARR,2,2)  \
    RXQs(ARR,3,3) RXQs(ARR,4,4) RXDs(ARR,DPP1,5)                        \
    RXD_W(ARR,DPP2,6,BUF,(CW2 ^ OW2K(k))) }
#define RXHIGH_N(ARR) { RXQs(ARR,0,0) RXQs(ARR,1,1) RXQs(ARR,2,2)       \
    RXQs(ARR,3,3) RXQs(ARR,4,4) RXDs(ARR,DPP1,5) RXDs(ARR,DPP2,6) }

// Product-state encoding fused with layer-0 CNOT perm, into P0 registers.
#define ENCODE(ARR, TBL) {                                              \
    float base_ = 1.0f;                                                 \
    _Pragma("unroll") for (int q = 6; q < NQ; ++q) {                    \
        float2 f_ = (TBL)[q];                                           \
        base_ *= ((Tm >> (q - 5)) & 1) ? f_.x : f_.y; }                 \
    float2 f5_ = (TBL)[5];                                              \
    float g5a_ = (t & 1) ? f5_.x : f5_.y;                               \
    float g5b_ = (t & 1) ? f5_.y : f5_.x;                               \
    float2 f0_ = (TBL)[0], f1_ = (TBL)[1], f2_ = (TBL)[2],              \
           f3_ = (TBL)[3], f4_ = (TBL)[4];                              \
    _Pragma("unroll") for (int o = 0; o < APT; ++o) {                   \
        const int op_ = o ^ (o << 1);                                   \
        float v_ = base_ * ((op_ & 32) ? g5b_ : g5a_);                  \
        v_ *= (op_ & 1)  ? f0_.x : f0_.y;                               \
        v_ *= (op_ & 2)  ? f1_.x : f1_.y;                               \
        v_ *= (op_ & 4)  ? f2_.x : f2_.y;                               \
        v_ *= (op_ & 8)  ? f3_.x : f3_.y;                               \
        v_ *= (op_ & 16) ? f4_.x : f4_.y;                               \
        ARR[o] = __floats2half2_rn(v_, 0.0f); } }

// Z-expectation partials from P1 layout -> RED[wave*12 + 0..11]
#define EXPECT(ARR, RED) {                                              \
    float ptot = 0.f, Sq[5] = {0, 0, 0, 0, 0};                          \
    _Pragma("unroll") for (int o = 0; o < APT; ++o) {                   \
        float2 f_ = __half22float2(ARR[o]);                             \
        float p_ = f_.x * f_.x + f_.y * f_.y;                           \
        ptot += p_;                                                     \
        _Pragma("unroll") for (int m = 0; m < 5; ++m)                   \
            Sq[m] += ((o >> m) & 1) ? -p_ : p_; }                       \
    float accL[6];                                                      \
    _Pragma("unroll") for (int k = 0; k < 6; ++k) accL[k] = ptot;       \
    _Pragma("unroll") for (int k = 0; k < 6; ++k) {                     \
        _Pragma("unroll") for (int j = 0; j < 6; ++j) {                 \
            float pr_ = SHX(accL[j], k);                                \
            if (j == k) accL[j] = ((lane >> k) & 1) ? (pr_ - accL[j])   \
                                                    : (accL[j] - pr_);  \
            else accL[j] += pr_; }                                      \
        ptot += SHX(ptot, k);                                           \
        _Pragma("unroll") for (int j2 = 0; j2 < 5; ++j2)                \
            Sq[j2] += SHX(Sq[j2], k); }                                 \
    if (lane == 0) {                                                    \
        (RED)[wv * 12 + 0] = ptot;                                      \
        _Pragma("unroll") for (int k = 0; k < 6; ++k) (RED)[wv * 12 + 1 + k] = accL[k]; \
        _Pragma("unroll") for (int m2 = 0; m2 < 5; ++m2) (RED)[wv * 12 + 7 + m2] = Sq[m2]; } }

__global__ __launch_bounds__(NT, 2)
void vqc_kernel(const float* __restrict__ inputs,
                const float* __restrict__ weights,
                float* __restrict__ out)
{
    extern __shared__ __half2 lds[];   // buf0 | buf1 | wtab | itab | redA | redB
    const int t    = threadIdx.x;
    const int b    = blockIdx.x;
    const int lane = t & 63;
    const int wv   = t >> 6;
    const int sA   = 2 * b, sB = 2 * b + 1;
    const int Tm   = (t ^ (t << 1)) & 0x3FF;

    __half2* buf0 = lds;
    __half2* buf1 = lds + DIM;
    uint2*   wtab = reinterpret_cast<uint2*>(lds + 2 * DIM);   // 56
    float2*  itab = reinterpret_cast<float2*>(wtab + 56);      // 28
    float*   redA = reinterpret_cast<float*>(itab + 28);       // 96
    float*   redB = redA + 96;                                 // 96

    const int t0 = t & 1, t1 = (t >> 1) & 1, t2 = (t >> 2) & 1, t3 = (t >> 3) & 1,
              t4 = (t >> 4) & 1, t5 = (t >> 5) & 1, t6 = (t >> 6) & 1,
              t7 = (t >> 7) & 1, t8 = (t >> 8) & 1;

    // Thread-constant address bases (maps A,B; v11-validated).
    const int CW1 = ((t & 63) << 1) ^ (t6 ? 8192 : 0) ^ (t7 ? 1040 : 0) ^ (t8 ? 2048 : 0);
    const int CR1 = (t0 ? 1040 : 0) ^ (t1 ? 2048 : 0) ^ (t2 ? 1 : 0) ^ (t3 ? 130 : 0)
                  ^ (t4 ? 260 : 0) ^ (t5 ? 520 : 0) ^ (t6 ? 4096 : 0)
                  ^ (t7 ? 2 : 0) ^ (t8 ? 4 : 0);
    const int CW2 = ((t & 63) << 1) ^ (t6 ? 8192 : 0) ^ (t7 ? 128 : 0) ^ (t8 ? 258 : 0);
    const int CR2 = (t0 ? 386 : 0) ^ (t1 ? 259 : 0) ^ (t2 ? 517 : 0) ^ (t3 ? 1544 : 0)
                  ^ (t4 ? 3088 : 0) ^ (t5 ? 6144 : 0) ^ (t6 ? 4126 : 0)
                  ^ (t7 ? 6 : 0) ^ (t8 ? 4 : 0);

    // Sincos tables: wave0 does weights (sp,cc packed), wave1 does inputs.
    if (t < NL * NQ) {
        float s_, c_;
        __sincosf(0.5f * weights[t], &s_, &c_);
        wtab[t] = make_uint2(H2U(__floats2half2_rn(s_, -s_)), H2U(__float2half2_rn(c_)));
    }
    if (t >= 64 && t < 64 + 2 * NQ) {
        int i_ = t - 64;
        int si_ = (i_ >= NQ) ? 1 : 0;
        float s_, c_;
        __sincosf(0.5f * inputs[(sA + si_) * NQ + (i_ - NQ * si_)], &s_, &c_);
        itab[i_] = make_float2(s_, c_);
    }
    __syncthreads();

    int sw[7], cw[7];           // current 7-qubit coefficient block (SGPRs)
    __half2 aA[APT], aB[APT];

    PRELOADW(0, 0);
    // p0
    ENCODE(aA, itab);  RXLOW_F(aA, buf0);                       __syncthreads();
    // p1
    RS1(aA, buf0);  ENCODE(aB, itab + NQ);  RXLOW_F(aB, buf1);  PRELOADW(0, 7); __syncthreads();
    // p2
    RS1(aB, buf1);  RXHIGH_F(aA, buf0);                         __syncthreads();
    // p3
    RS2(aA, buf0);  RXHIGH_F(aB, buf1);  PRELOADW(1, 0);        __syncthreads();

#pragma unroll 1
    for (int l = 1; l < NL - 1; ++l) {
        RS2(aB, buf1);  RXLOW_F(aA, buf0);                      __syncthreads();
        RS1(aA, buf0);  RXLOW_F(aB, buf1);  PRELOADW(l, 7);     __syncthreads();
        RS1(aB, buf1);  RXHIGH_F(aA, buf0);                     __syncthreads();
        RS2(aA, buf0);  RXHIGH_F(aB, buf1); PRELOADW(l + 1, 0); __syncthreads();
    }
    // tail: layer 3
    RS2(aB, buf1);  RXLOW_F(aA, buf0);                          __syncthreads();
    RS1(aA, buf0);  RXLOW_F(aB, buf1);  PRELOADW(3, 7);         __syncthreads();
    RS1(aB, buf1);  RXHIGH_N(aA);  RXHIGH_N(aB);

    EXPECT(aA, redA);
    EXPECT(aB, redB);
    __syncthreads();

    // Cross-wave combine. P1: lane2-5 = q0-3, wave bits = q4-6, o = q7-11,
    // lane0,1 = q12,13.
    if (t < NQ) {
        float accA = 0.f, accB = 0.f;
#pragma unroll 1
        for (int w = 0; w < 8; ++w) {
            float vA, vB;
            if (t < 4)       { vA = redA[w * 12 + 3 + t];        vB = redB[w * 12 + 3 + t]; }
            else if (t < 7)  { vA = redA[w * 12];                vB = redB[w * 12];
                               if ((w >> (t - 4)) & 1) { vA = -vA; vB = -vB; } }
            else if (t < 12) { vA = redA[w * 12 + 7 + (t - 7)];  vB = redB[w * 12 + 7 + (t - 7)]; }
            else             { vA = redA[w * 12 + 1 + (t - 12)]; vB = redB[w * 12 + 1 + (t - 12)]; }
            accA += vA; accB += vB;
        }
        out[sA * NQ + t] = accA;
        out[sB * NQ + t] = accB;
    }
}

extern "C" void kernel_launch(void* const* d_in, const int* in_sizes, int n_in,
                              void* d_out, int out_size, void* d_ws, size_t ws_size,
                              hipStream_t stream)
{
    const float* inputs  = (const float*)d_in[0];
    const float* weights = (const float*)d_in[1];
    float* out = (float*)d_out;

    const int Bn = in_sizes[0] / NQ;   // 1024
    const size_t shmem = 2 * DIM * sizeof(__half2)
                       + 56 * sizeof(uint2) + 28 * sizeof(float2)
                       + 192 * sizeof(float);
    vqc_kernel<<<dim3(Bn / 2), dim3(NT), shmem, stream>>>(inputs, weights, out);
}